// Round 9
// baseline (793.894 us; speedup 1.0000x reference)
//
#include <hip/hip_runtime.h>
#include <hip/hip_bf16.h>
#include <stdint.h>

#define B_DIM 32
#define T_DIM 2048
#define H_DIM 1024
#define M_DIM (B_DIM * T_DIM)   // 65536
#define K_DIM H_DIM              // 1024
#define N_DIM H_DIM              // 1024

// GEMM geometry
#define BM 256
#define BN 256
#define BKT 32
#define NTILES (K_DIM / BKT)     // 32
#define DEPTH 3                  // tiles prefetched ahead (4 LDS buffers)

typedef __attribute__((ext_vector_type(4))) float f32x4;
typedef __attribute__((ext_vector_type(8))) short short8;

__device__ __forceinline__ unsigned short f2bf(float x) {
  unsigned u = __float_as_uint(x);
  return (unsigned short)((u + 0x7FFFu + ((u >> 16) & 1u)) >> 16);
}
__device__ __forceinline__ float bf2f(unsigned short h) {
  return __uint_as_float(((unsigned)h) << 16);
}
__device__ __forceinline__ float fast_tanh(float x) {
  float e = __expf(2.f * x);
  return 1.f - 2.f / (e + 1.f);
}
// Swizzled byte offset of 16B slot s (0..3) of row r in a [256][32]bf16 tile.
// Verified R3/R6: SQ_LDS_BANK_CONFLICT == 0.
__device__ __forceinline__ int swz(int r, int s) {
  return ((r >> 1) << 7) + (((((r & 1) << 2) | s) ^ ((r >> 1) & 7)) << 4);
}

// ---------------- convert G (fp32 -> bf16), grid-stride ----------------
__global__ void convert_g_kernel(const float* __restrict__ in,
                                 unsigned short* __restrict__ out) {
  size_t nvec = (size_t)M_DIM * K_DIM / 8;
  size_t stride = (size_t)gridDim.x * blockDim.x;
  for (size_t i = (size_t)blockIdx.x * blockDim.x + threadIdx.x; i < nvec;
       i += stride) {
    const float4* p = (const float4*)(in + i * 8);
    float4 u0 = p[0], u1 = p[1];
    short8 s;
    s[0] = (short)f2bf(u0.x); s[1] = (short)f2bf(u0.y);
    s[2] = (short)f2bf(u0.z); s[3] = (short)f2bf(u0.w);
    s[4] = (short)f2bf(u1.x); s[5] = (short)f2bf(u1.y);
    s[6] = (short)f2bf(u1.z); s[7] = (short)f2bf(u1.w);
    *(short8*)(out + i * 8) = s;
  }
}

// ------- convert + transpose W via LDS: Wt[n][k] = bf16(W[k][n]) -------
__global__ void convert_w_kernel(const float* __restrict__ w,
                                 unsigned short* __restrict__ wt) {
  __shared__ float tile[64][65];
  int n0 = blockIdx.x * 64;
  int k0 = blockIdx.y * 64;
  int j = threadIdx.x & 63;
  int i0 = threadIdx.x >> 6;  // 0..3
#pragma unroll
  for (int ii = 0; ii < 16; ++ii) {
    int i = i0 * 16 + ii;
    tile[i][j] = w[(size_t)(k0 + i) * H_DIM + n0 + j];
  }
  __syncthreads();
#pragma unroll
  for (int ii = 0; ii < 16; ++ii) {
    int i = i0 * 16 + ii;
    wt[(size_t)(n0 + i) * H_DIM + k0 + j] = f2bf(tile[j][i]);
  }
}

// ---- GEMM: logits[row] += sum_col c[col] * tanh( A[row,:] . Bt[col,:] ) ----
// 256x256 tile, BK=32, 8 waves (2M x 4N), 4-deep circular LDS prefetch,
// counted vmcnt (T4), both-sides swizzle (T2), setprio (T5).
// R9: one-phase-ahead register prefetch of MFMA operands (ds_reads overlap
// MFMA on the LDS pipe) + single barrier per K-tile (buffers read/written
// per tile are disjoint mod 4; lgkmcnt(0) drain before barrier closes the
// read-vs-overwrite race). XCD map reverted to R6's (R8 regressed).
__global__ __launch_bounds__(512, 2) void gemm_tanh_logits(
    const unsigned short* __restrict__ A,
    const unsigned short* __restrict__ Bt,
    const float* __restrict__ cvec,
    float* __restrict__ logits) {
  // 4 buffers x (A-half 8192 + B-half 8192) ushorts = 128 KB
  __shared__ unsigned short lds[4 * 16384];

  const int tid = threadIdx.x;
  const int wid = tid >> 6;
  const int lane = tid & 63;

  // R6 XCD-aware swizzle: 1024 blocks, 8 XCDs, 128 contiguous logical per
  // XCD; the 4 ncols of one mrow are consecutive logicals -> same XCD ->
  // A-panel 4x reuse in that XCD's L2. (R8's inversion: FETCH 98->270MB.)
  int p = blockIdx.x;
  int logical = (p & 7) * 128 + (p >> 3);
  int mrow = logical >> 2;  // 0..255
  int ncol = logical & 3;   // 0..3

  const unsigned short* Ap = A + (size_t)mrow * BM * K_DIM;
  const unsigned short* Bp = Bt + (size_t)ncol * BN * K_DIM;

  // Hoisted per-thread staging source pointers (swizzle pre-decoded once).
  const unsigned short *gA[2], *gB[2];
#pragma unroll
  for (int j = 0; j < 2; ++j) {
    int o = j * 8192 + tid * 16;        // byte offset within 16KB half
    int pr = o >> 7;                    // row pair
    int v = ((o >> 4) & 7) ^ (pr & 7);  // undo swizzle
    int r = (pr << 1) | (v >> 2);
    int s = v & 3;
    gA[j] = Ap + (size_t)r * K_DIM + s * 8;
    gB[j] = Bp + (size_t)r * K_DIM + s * 8;
  }
  const int ldst0 = wid * 512;           // ushort offset, j=0
  const int ldst1 = wid * 512 + 4096;    // ushort offset, j=1

  auto stageA = [&](int tt, int bi) {
    __builtin_amdgcn_global_load_lds(
        (const __attribute__((address_space(1))) unsigned int*)(gA[0] + tt * BKT),
        (__attribute__((address_space(3))) unsigned int*)(lds + bi * 16384 + ldst0),
        16, 0, 0);
    __builtin_amdgcn_global_load_lds(
        (const __attribute__((address_space(1))) unsigned int*)(gA[1] + tt * BKT),
        (__attribute__((address_space(3))) unsigned int*)(lds + bi * 16384 + ldst1),
        16, 0, 0);
  };
  auto stageB = [&](int tt, int bi) {
    __builtin_amdgcn_global_load_lds(
        (const __attribute__((address_space(1))) unsigned int*)(gB[0] + tt * BKT),
        (__attribute__((address_space(3))) unsigned int*)(lds + bi * 16384 + 8192 + ldst0),
        16, 0, 0);
    __builtin_amdgcn_global_load_lds(
        (const __attribute__((address_space(1))) unsigned int*)(gB[1] + tt * BKT),
        (__attribute__((address_space(3))) unsigned int*)(lds + bi * 16384 + 8192 + ldst1),
        16, 0, 0);
  };

  const int wm = wid >> 2;  // 0..1 -> rows wm*128..+128
  const int wn = wid & 3;   // 0..3 -> cols wn*64..+64
  const int fr = lane & 15;
  const int sl = lane >> 4;

  const int aoff = swz(wm * 128 + fr, sl) >> 1;        // ushort units
  const int boff = (swz(wn * 64 + fr, sl) >> 1) + 8192;

  f32x4 acc[8][4];
#pragma unroll
  for (int m = 0; m < 8; ++m)
#pragma unroll
    for (int n = 0; n < 4; ++n) acc[m][n] = (f32x4){0.f, 0.f, 0.f, 0.f};

  // ping-pong operand sets (static indices after unroll -> registers)
  short8 ra[2][4], rb[2][4];

  // prologue: stage tiles 0..2; wait tile 0 (8 newest in flight); preload t0
  stageA(0, 0); stageB(0, 0);
  stageA(1, 1); stageB(1, 1);
  stageA(2, 2); stageB(2, 2);
  asm volatile("s_waitcnt vmcnt(8)" ::: "memory");
  __builtin_amdgcn_s_barrier();
#pragma unroll
  for (int m = 0; m < 4; ++m) ra[0][m] = *(const short8*)(lds + aoff + m * 512);
#pragma unroll
  for (int n = 0; n < 4; ++n) rb[0][n] = *(const short8*)(lds + boff + n * 512);

  for (int T = 0; T < NTILES; T += 4) {
#pragma unroll
    for (int u = 0; u < 4; ++u) {
      const int t = T + u;
      const int cs = u & 1, ns = cs ^ 1;
      const unsigned short* L0 = lds + u * 16384;              // tile t
      const unsigned short* L1 = lds + ((u + 1) & 3) * 16384;  // tile t+1
      short8 rx[4];
      // ---- PHASE A: issue phase-B reads + stage; MFMA on preloaded set
#pragma unroll
      for (int m = 0; m < 4; ++m)
        rx[m] = *(const short8*)(L0 + aoff + (m + 4) * 512);
      if (t + DEPTH < NTILES) stageA(t + DEPTH, (u + 3) & 3);
      __builtin_amdgcn_s_setprio(1);
#pragma unroll
      for (int m = 0; m < 4; ++m)
#pragma unroll
        for (int n = 0; n < 4; ++n)
          acc[m][n] = __builtin_amdgcn_mfma_f32_16x16x32_bf16(
              ra[cs][m], rb[cs][n], acc[m][n], 0, 0, 0);
      __builtin_amdgcn_s_setprio(0);
      // ---- PHASE B: stage; counted vmcnt; single barrier; preload t+1;
      //      MFMA (rx) overlaps the preload reads.
      if (t + DEPTH < NTILES) stageB(t + DEPTH, (u + 3) & 3);
      if (t < NTILES - DEPTH)
        asm volatile("s_waitcnt vmcnt(8)" ::: "memory");
      else if (t == NTILES - DEPTH)
        asm volatile("s_waitcnt vmcnt(4)" ::: "memory");
      else if (t == NTILES - 2)
        asm volatile("s_waitcnt vmcnt(0)" ::: "memory");
      asm volatile("s_waitcnt lgkmcnt(0)" ::: "memory");  // drain reads of
      __builtin_amdgcn_s_barrier();  // bufs about to be overwritten (race fix)
      if (t + 1 < NTILES) {
#pragma unroll
        for (int m = 0; m < 4; ++m)
          ra[ns][m] = *(const short8*)(L1 + aoff + m * 512);
#pragma unroll
        for (int n = 0; n < 4; ++n)
          rb[ns][n] = *(const short8*)(L1 + boff + n * 512);
      }
      __builtin_amdgcn_s_setprio(1);
#pragma unroll
      for (int m = 0; m < 4; ++m)
#pragma unroll
        for (int n = 0; n < 4; ++n)
          acc[m + 4][n] = __builtin_amdgcn_mfma_f32_16x16x32_bf16(
              rx[m], rb[cs][n], acc[m + 4][n], 0, 0, 0);
      __builtin_amdgcn_s_setprio(0);
    }
  }

  // epilogue: logits[row] += sum_cols c[col]*tanh(acc)
  // C/D layout: col = lane&15, row = (lane>>4)*4 + j
  const int cgrp = lane >> 4;
  const int cidx = lane & 15;
  const int colb = ncol * BN + wn * 64;
  const int rowb = mrow * BM + wm * 128;
  float cw[4];
#pragma unroll
  for (int n = 0; n < 4; ++n) cw[n] = cvec[colb + n * 16 + cidx];
#pragma unroll
  for (int m = 0; m < 8; ++m) {
    float s0 = 0.f, s1 = 0.f, s2 = 0.f, s3 = 0.f;
#pragma unroll
    for (int n = 0; n < 4; ++n) {
      s0 += fast_tanh(acc[m][n][0]) * cw[n];
      s1 += fast_tanh(acc[m][n][1]) * cw[n];
      s2 += fast_tanh(acc[m][n][2]) * cw[n];
      s3 += fast_tanh(acc[m][n][3]) * cw[n];
    }
#pragma unroll
    for (int mask = 1; mask < 16; mask <<= 1) {
      s0 += __shfl_xor(s0, mask);
      s1 += __shfl_xor(s1, mask);
      s2 += __shfl_xor(s2, mask);
      s3 += __shfl_xor(s3, mask);
    }
    if (cidx == 0) {
      int row = rowb + m * 16 + cgrp * 4;
      atomicAdd(&logits[row + 0], s0);
      atomicAdd(&logits[row + 1], s1);
      atomicAdd(&logits[row + 2], s2);
      atomicAdd(&logits[row + 3], s3);
    }
  }
}

// -------- softmax over T (2048) per batch row, in-place on logits ----------
__global__ void softmax_kernel(float* __restrict__ la) {
  int b = blockIdx.x;
  float* row = la + (size_t)b * T_DIM;
  int tid = threadIdx.x;
  int wid = tid >> 6, lane = tid & 63;
  __shared__ float red[4];

  float v[8];
  float mx = -3.4e38f;
#pragma unroll
  for (int i = 0; i < 8; ++i) {
    v[i] = row[tid + i * 256];
    mx = fmaxf(mx, v[i]);
  }
#pragma unroll
  for (int mask = 32; mask >= 1; mask >>= 1) mx = fmaxf(mx, __shfl_xor(mx, mask));
  if (lane == 0) red[wid] = mx;
  __syncthreads();
  mx = fmaxf(fmaxf(red[0], red[1]), fmaxf(red[2], red[3]));
  __syncthreads();

  float sum = 0.f;
#pragma unroll
  for (int i = 0; i < 8; ++i) {
    v[i] = __expf(v[i] - mx);
    sum += v[i];
  }
#pragma unroll
  for (int mask = 32; mask >= 1; mask >>= 1) sum += __shfl_xor(sum, mask);
  if (lane == 0) red[wid] = sum;
  __syncthreads();
  sum = red[0] + red[1] + red[2] + red[3];
  float inv = 1.f / sum;
#pragma unroll
  for (int i = 0; i < 8; ++i) row[tid + i * 256] = v[i] * inv;
}

// --- context[b][h] = sum_t attn[b][t]*G[b][t][h], bf16 G, 16B/lane loads ---
__global__ void context_kernel(const unsigned short* __restrict__ Gb,
                               const float* __restrict__ attn,
                               float* __restrict__ ctx) {
  int tc = blockIdx.x;             // 0..7 (256 t each)
  int b = blockIdx.y;              // 0..31
  int th = threadIdx.x >> 7;       // 0..1 -> t-half of 128
  int h = (threadIdx.x & 127) * 8; // 0..1016
  const unsigned short* g =
      Gb + ((size_t)b * T_DIM + tc * 256 + th * 128) * H_DIM + h;
  const float* a = attn + b * T_DIM + tc * 256 + th * 128;
  float s[8];
#pragma unroll
  for (int j = 0; j < 8; ++j) s[j] = 0.f;
#pragma unroll 4
  for (int t = 0; t < 128; ++t) {
    short8 v = *(const short8*)(g + (size_t)t * H_DIM);
    float w = a[t];
#pragma unroll
    for (int j = 0; j < 8; ++j) s[j] += w * bf2f((unsigned short)v[j]);
  }
  float* cb = ctx + b * H_DIM + h;
#pragma unroll
  for (int j = 0; j < 8; ++j) atomicAdd(cb + j, s[j]);
}

extern "C" void kernel_launch(void* const* d_in, const int* in_sizes, int n_in,
                              void* d_out, int out_size, void* d_ws, size_t ws_size,
                              hipStream_t stream) {
  const float* G = (const float*)d_in[0];  // [32][2048][1024]
  const float* W = (const float*)d_in[1];  // [1024][1024]
  const float* c = (const float*)d_in[2];  // [1024]
  float* out = (float*)d_out;
  float* ctx = out;                         // [32][1024]
  float* attn = out + B_DIM * H_DIM;        // [32][2048] logits -> attn

  unsigned short* Gb = (unsigned short*)d_ws;                        // 128MB
  unsigned short* Wt = (unsigned short*)((char*)d_ws +
                                         (size_t)M_DIM * K_DIM * 2);  // 2MB

  hipMemsetAsync(d_out, 0, (size_t)out_size * sizeof(float), stream);

  convert_g_kernel<<<4096, 256, 0, stream>>>(G, Gb);
  convert_w_kernel<<<dim3(16, 16), 256, 0, stream>>>(W, Wt);
  gemm_tanh_logits<<<1024, 512, 0, stream>>>(Gb, Wt, c, attn);
  softmax_kernel<<<B_DIM, 256, 0, stream>>>(attn);
  context_kernel<<<dim3(8, 32), 256, 0, stream>>>(Gb, attn, ctx);
}

// Round 10
// 762.087 us; speedup vs baseline: 1.0417x; 1.0417x over previous
//
#include <hip/hip_runtime.h>
#include <hip/hip_bf16.h>
#include <stdint.h>

#define B_DIM 32
#define T_DIM 2048
#define H_DIM 1024
#define M_DIM (B_DIM * T_DIM)   // 65536
#define K_DIM H_DIM              // 1024
#define N_DIM H_DIM              // 1024

#define BM 256
#define BN 256
#define BKT 32
#define NTILES (K_DIM / BKT)     // 32
#define DEPTH 3                  // tiles staged ahead (4 LDS buffers)

typedef __attribute__((ext_vector_type(4))) float f32x4;
typedef __attribute__((ext_vector_type(8))) short short8;

__device__ __forceinline__ unsigned short f2bf(float x) {
  unsigned u = __float_as_uint(x);
  return (unsigned short)((u + 0x7FFFu + ((u >> 16) & 1u)) >> 16);
}
__device__ __forceinline__ float bf2f(unsigned short h) {
  return __uint_as_float(((unsigned)h) << 16);
}
__device__ __forceinline__ float fast_tanh(float x) {
  float e = __expf(2.f * x);
  return 1.f - 2.f / (e + 1.f);
}
// Swizzled byte offset of 16B slot s (0..3) of row r in a [256][32]bf16 tile.
// Verified R3/R6: SQ_LDS_BANK_CONFLICT == 0.
__device__ __forceinline__ int swz(int r, int s) {
  return ((r >> 1) << 7) + (((((r & 1) << 2) | s) ^ ((r >> 1) & 7)) << 4);
}

// ---------------- convert G (fp32 -> bf16), grid-stride ----------------
__global__ void convert_g_kernel(const float* __restrict__ in,
                                 unsigned short* __restrict__ out) {
  size_t nvec = (size_t)M_DIM * K_DIM / 8;
  size_t stride = (size_t)gridDim.x * blockDim.x;
  for (size_t i = (size_t)blockIdx.x * blockDim.x + threadIdx.x; i < nvec;
       i += stride) {
    const float4* p = (const float4*)(in + i * 8);
    float4 u0 = p[0], u1 = p[1];
    short8 s;
    s[0] = (short)f2bf(u0.x); s[1] = (short)f2bf(u0.y);
    s[2] = (short)f2bf(u0.z); s[3] = (short)f2bf(u0.w);
    s[4] = (short)f2bf(u1.x); s[5] = (short)f2bf(u1.y);
    s[6] = (short)f2bf(u1.z); s[7] = (short)f2bf(u1.w);
    *(short8*)(out + i * 8) = s;
  }
}

// ------- convert + transpose W via LDS: Wt[n][k] = bf16(W[k][n]) -------
__global__ void convert_w_kernel(const float* __restrict__ w,
                                 unsigned short* __restrict__ wt) {
  __shared__ float tile[64][65];
  int n0 = blockIdx.x * 64;
  int k0 = blockIdx.y * 64;
  int j = threadIdx.x & 63;
  int i0 = threadIdx.x >> 6;  // 0..3
#pragma unroll
  for (int ii = 0; ii < 16; ++ii) {
    int i = i0 * 16 + ii;
    tile[i][j] = w[(size_t)(k0 + i) * H_DIM + n0 + j];
  }
  __syncthreads();
#pragma unroll
  for (int ii = 0; ii < 16; ++ii) {
    int i = i0 * 16 + ii;
    wt[(size_t)(n0 + i) * H_DIM + k0 + j] = f2bf(tile[j][i]);
  }
}

// ---- GEMM: logits[row] += sum_col c[col] * tanh( A[row,:] . Bt[col,:] ) ----
// R10: half-tile modulo pipeline. Reads of tile t+1 issue under tile t's H1
// MFMAs; counted lgkmcnt(4/8), one barrier + counted vmcnt(4) per K-tile.
// Peak live operand frags = 16 (64 VGPR) vs R9's ~24 (spilled, WRITE 467MB).
__global__ __launch_bounds__(512, 2) void gemm_tanh_logits(
    const unsigned short* __restrict__ A,
    const unsigned short* __restrict__ Bt,
    const float* __restrict__ cvec,
    float* __restrict__ logits) {
  __shared__ unsigned short lds[4 * 16384];  // 4 bufs x (A 16KB + B 16KB)

  const int tid = threadIdx.x;
  const int wid = tid >> 6;
  const int lane = tid & 63;

  // R6 XCD map (verified): 4 ncols of one mrow land on one XCD -> A L2-reuse.
  int p = blockIdx.x;
  int logical = (p & 7) * 128 + (p >> 3);
  int mrow = logical >> 2;  // 0..255
  int ncol = logical & 3;   // 0..3

  const unsigned short* Ap = A + (size_t)mrow * BM * K_DIM;
  const unsigned short* Bp = Bt + (size_t)ncol * BN * K_DIM;

  const unsigned short *gA[2], *gB[2];
#pragma unroll
  for (int j = 0; j < 2; ++j) {
    int o = j * 8192 + tid * 16;
    int pr = o >> 7;
    int v = ((o >> 4) & 7) ^ (pr & 7);
    int r = (pr << 1) | (v >> 2);
    int s = v & 3;
    gA[j] = Ap + (size_t)r * K_DIM + s * 8;
    gB[j] = Bp + (size_t)r * K_DIM + s * 8;
  }
  const int ldst0 = wid * 512;
  const int ldst1 = wid * 512 + 4096;

  auto stageA = [&](int tt, int bi) {
    __builtin_amdgcn_global_load_lds(
        (const __attribute__((address_space(1))) unsigned int*)(gA[0] + tt * BKT),
        (__attribute__((address_space(3))) unsigned int*)(lds + bi * 16384 + ldst0),
        16, 0, 0);
    __builtin_amdgcn_global_load_lds(
        (const __attribute__((address_space(1))) unsigned int*)(gA[1] + tt * BKT),
        (__attribute__((address_space(3))) unsigned int*)(lds + bi * 16384 + ldst1),
        16, 0, 0);
  };
  auto stageB = [&](int tt, int bi) {
    __builtin_amdgcn_global_load_lds(
        (const __attribute__((address_space(1))) unsigned int*)(gB[0] + tt * BKT),
        (__attribute__((address_space(3))) unsigned int*)(lds + bi * 16384 + 8192 + ldst0),
        16, 0, 0);
    __builtin_amdgcn_global_load_lds(
        (const __attribute__((address_space(1))) unsigned int*)(gB[1] + tt * BKT),
        (__attribute__((address_space(3))) unsigned int*)(lds + bi * 16384 + 8192 + ldst1),
        16, 0, 0);
  };

  const int wm = wid >> 2;
  const int wn = wid & 3;
  const int fr = lane & 15;
  const int sl = lane >> 4;

  const int aoff = swz(wm * 128 + fr, sl) >> 1;
  const int boff = (swz(wn * 64 + fr, sl) >> 1) + 8192;

  f32x4 acc[8][4];
#pragma unroll
  for (int m = 0; m < 8; ++m)
#pragma unroll
    for (int n = 0; n < 4; ++n) acc[m][n] = (f32x4){0.f, 0.f, 0.f, 0.f};

  short8 Xa[8], Xb[4], Ya[8], Yb[4];

  // prologue: stage tiles 0..2; vmcnt(4) -> tiles 0 AND 1 landed; barrier;
  // preload tile 0's b + a0-3 into X.
  stageA(0, 0); stageB(0, 0);
  stageA(1, 1); stageB(1, 1);
  stageA(2, 2); stageB(2, 2);
  asm volatile("s_waitcnt vmcnt(4)" ::: "memory");
  __builtin_amdgcn_s_barrier();
#pragma unroll
  for (int n = 0; n < 4; ++n) Xb[n] = *(const short8*)(lds + boff + n * 512);
#pragma unroll
  for (int m = 0; m < 4; ++m) Xa[m] = *(const short8*)(lds + aoff + m * 512);

  // Iteration t (cur set CA/CB holds tile t's b,a0-3; next set NA/NB):
  //  stage(t+3) -> buf (t-1)&3   [safe: B_{t-1} certified t-1 reads drained]
  //  read a4-7(t); lgkmcnt(4); MFMA H0;
  //  read b',a0-3'(t+1); lgkmcnt(8); MFMA H1;   [reads fly under H1]
  //  vmcnt(4) [t+2 landed]; barrier.
#define GITER(t, u, CA, CB, NA, NB)                                          \
  {                                                                          \
    const unsigned short* Lc = lds + (u) * 16384;                            \
    const unsigned short* Ln = lds + (((u) + 1) & 3) * 16384;                \
    if ((t) + DEPTH < NTILES) {                                              \
      stageA((t) + DEPTH, ((u) + 3) & 3);                                    \
      stageB((t) + DEPTH, ((u) + 3) & 3);                                    \
    }                                                                        \
    _Pragma("unroll") for (int m = 0; m < 4; ++m)                            \
        CA[m + 4] = *(const short8*)(Lc + aoff + (m + 4) * 512);             \
    asm volatile("s_waitcnt lgkmcnt(4)" ::: "memory");                       \
    __builtin_amdgcn_sched_barrier(0);                                       \
    __builtin_amdgcn_s_setprio(1);                                           \
    _Pragma("unroll") for (int m = 0; m < 4; ++m)                            \
        _Pragma("unroll") for (int n = 0; n < 4; ++n)                        \
        acc[m][n] = __builtin_amdgcn_mfma_f32_16x16x32_bf16(                 \
            CA[m], CB[n], acc[m][n], 0, 0, 0);                               \
    __builtin_amdgcn_s_setprio(0);                                           \
    __builtin_amdgcn_sched_barrier(0);                                       \
    if ((t) + 1 < NTILES) {                                                  \
      _Pragma("unroll") for (int n = 0; n < 4; ++n)                          \
          NB[n] = *(const short8*)(Ln + boff + n * 512);                     \
      _Pragma("unroll") for (int m = 0; m < 4; ++m)                          \
          NA[m] = *(const short8*)(Ln + aoff + m * 512);                     \
      asm volatile("s_waitcnt lgkmcnt(8)" ::: "memory");                     \
    } else {                                                                 \
      asm volatile("s_waitcnt lgkmcnt(0)" ::: "memory");                     \
    }                                                                        \
    __builtin_amdgcn_sched_barrier(0);                                       \
    __builtin_amdgcn_s_setprio(1);                                           \
    _Pragma("unroll") for (int m = 0; m < 4; ++m)                            \
        _Pragma("unroll") for (int n = 0; n < 4; ++n)                        \
        acc[m + 4][n] = __builtin_amdgcn_mfma_f32_16x16x32_bf16(             \
            CA[m + 4], CB[n], acc[m + 4][n], 0, 0, 0);                       \
    __builtin_amdgcn_s_setprio(0);                                           \
    __builtin_amdgcn_sched_barrier(0);                                       \
    if ((t) < NTILES - 2)                                                    \
      asm volatile("s_waitcnt vmcnt(4)" ::: "memory");                       \
    else if ((t) == NTILES - 2)                                              \
      asm volatile("s_waitcnt vmcnt(0)" ::: "memory");                       \
    __builtin_amdgcn_s_barrier();                                            \
  }

  for (int T = 0; T < NTILES; T += 4) {
    GITER(T + 0, 0, Xa, Xb, Ya, Yb);
    GITER(T + 1, 1, Ya, Yb, Xa, Xb);
    GITER(T + 2, 2, Xa, Xb, Ya, Yb);
    GITER(T + 3, 3, Ya, Yb, Xa, Xb);
  }
#undef GITER

  // epilogue: logits[row] += sum_cols c[col]*tanh(acc)
  // C/D layout: col = lane&15, row = (lane>>4)*4 + j
  const int cgrp = lane >> 4;
  const int cidx = lane & 15;
  const int colb = ncol * BN + wn * 64;
  const int rowb = mrow * BM + wm * 128;
  float cw[4];
#pragma unroll
  for (int n = 0; n < 4; ++n) cw[n] = cvec[colb + n * 16 + cidx];
#pragma unroll
  for (int m = 0; m < 8; ++m) {
    float s0 = 0.f, s1 = 0.f, s2 = 0.f, s3 = 0.f;
#pragma unroll
    for (int n = 0; n < 4; ++n) {
      s0 += fast_tanh(acc[m][n][0]) * cw[n];
      s1 += fast_tanh(acc[m][n][1]) * cw[n];
      s2 += fast_tanh(acc[m][n][2]) * cw[n];
      s3 += fast_tanh(acc[m][n][3]) * cw[n];
    }
#pragma unroll
    for (int mask = 1; mask < 16; mask <<= 1) {
      s0 += __shfl_xor(s0, mask);
      s1 += __shfl_xor(s1, mask);
      s2 += __shfl_xor(s2, mask);
      s3 += __shfl_xor(s3, mask);
    }
    if (cidx == 0) {
      int row = rowb + m * 16 + cgrp * 4;
      atomicAdd(&logits[row + 0], s0);
      atomicAdd(&logits[row + 1], s1);
      atomicAdd(&logits[row + 2], s2);
      atomicAdd(&logits[row + 3], s3);
    }
  }
}

// -------- softmax over T (2048) per batch row, in-place on logits ----------
__global__ void softmax_kernel(float* __restrict__ la) {
  int b = blockIdx.x;
  float* row = la + (size_t)b * T_DIM;
  int tid = threadIdx.x;
  int wid = tid >> 6, lane = tid & 63;
  __shared__ float red[4];

  float v[8];
  float mx = -3.4e38f;
#pragma unroll
  for (int i = 0; i < 8; ++i) {
    v[i] = row[tid + i * 256];
    mx = fmaxf(mx, v[i]);
  }
#pragma unroll
  for (int mask = 32; mask >= 1; mask >>= 1) mx = fmaxf(mx, __shfl_xor(mx, mask));
  if (lane == 0) red[wid] = mx;
  __syncthreads();
  mx = fmaxf(fmaxf(red[0], red[1]), fmaxf(red[2], red[3]));
  __syncthreads();

  float sum = 0.f;
#pragma unroll
  for (int i = 0; i < 8; ++i) {
    v[i] = __expf(v[i] - mx);
    sum += v[i];
  }
#pragma unroll
  for (int mask = 32; mask >= 1; mask >>= 1) sum += __shfl_xor(sum, mask);
  if (lane == 0) red[wid] = sum;
  __syncthreads();
  sum = red[0] + red[1] + red[2] + red[3];
  float inv = 1.f / sum;
#pragma unroll
  for (int i = 0; i < 8; ++i) row[tid + i * 256] = v[i] * inv;
}

// --- context[b][h] = sum_t attn[b][t]*G[b][t][h], bf16 G, 16B/lane loads ---
__global__ void context_kernel(const unsigned short* __restrict__ Gb,
                               const float* __restrict__ attn,
                               float* __restrict__ ctx) {
  int tc = blockIdx.x;             // 0..7 (256 t each)
  int b = blockIdx.y;              // 0..31
  int th = threadIdx.x >> 7;       // 0..1 -> t-half of 128
  int h = (threadIdx.x & 127) * 8; // 0..1016
  const unsigned short* g =
      Gb + ((size_t)b * T_DIM + tc * 256 + th * 128) * H_DIM + h;
  const float* a = attn + b * T_DIM + tc * 256 + th * 128;
  float s[8];
#pragma unroll
  for (int j = 0; j < 8; ++j) s[j] = 0.f;
#pragma unroll 4
  for (int t = 0; t < 128; ++t) {
    short8 v = *(const short8*)(g + (size_t)t * H_DIM);
    float w = a[t];
#pragma unroll
    for (int j = 0; j < 8; ++j) s[j] += w * bf2f((unsigned short)v[j]);
  }
  float* cb = ctx + b * H_DIM + h;
#pragma unroll
  for (int j = 0; j < 8; ++j) atomicAdd(cb + j, s[j]);
}

extern "C" void kernel_launch(void* const* d_in, const int* in_sizes, int n_in,
                              void* d_out, int out_size, void* d_ws, size_t ws_size,
                              hipStream_t stream) {
  const float* G = (const float*)d_in[0];  // [32][2048][1024]
  const float* W = (const float*)d_in[1];  // [1024][1024]
  const float* c = (const float*)d_in[2];  // [1024]
  float* out = (float*)d_out;
  float* ctx = out;                         // [32][1024]
  float* attn = out + B_DIM * H_DIM;        // [32][2048] logits -> attn

  unsigned short* Gb = (unsigned short*)d_ws;                        // 128MB
  unsigned short* Wt = (unsigned short*)((char*)d_ws +
                                         (size_t)M_DIM * K_DIM * 2);  // 2MB

  hipMemsetAsync(d_out, 0, (size_t)out_size * sizeof(float), stream);

  convert_g_kernel<<<4096, 256, 0, stream>>>(G, Gb);
  convert_w_kernel<<<dim3(16, 16), 256, 0, stream>>>(W, Wt);
  gemm_tanh_logits<<<1024, 512, 0, stream>>>(Gb, Wt, c, attn);
  softmax_kernel<<<B_DIM, 256, 0, stream>>>(attn);
  context_kernel<<<dim3(8, 32), 256, 0, stream>>>(Gb, attn, ctx);
}

// Round 12
// 574.616 us; speedup vs baseline: 1.3816x; 1.3263x over previous
//
#include <hip/hip_runtime.h>
#include <hip/hip_bf16.h>
#include <stdint.h>

#define B_DIM 32
#define T_DIM 2048
#define H_DIM 1024
#define M_DIM (B_DIM * T_DIM)   // 65536
#define K_DIM H_DIM              // 1024
#define N_DIM H_DIM              // 1024

#define BM 256
#define BN 256
#define BKT 32
#define NTILES (K_DIM / BKT)     // 32
#define DEPTH 3                  // tiles staged ahead (4 LDS buffers)

typedef __attribute__((ext_vector_type(4))) float f32x4;
typedef __attribute__((ext_vector_type(8))) short short8;

__device__ __forceinline__ unsigned short f2bf(float x) {
  unsigned u = __float_as_uint(x);
  return (unsigned short)((u + 0x7FFFu + ((u >> 16) & 1u)) >> 16);
}
__device__ __forceinline__ float bf2f(unsigned short h) {
  return __uint_as_float(((unsigned)h) << 16);
}
__device__ __forceinline__ float fast_tanh(float x) {
  float e = __expf(2.f * x);
  return 1.f - 2.f / (e + 1.f);
}
// Swizzled byte offset of 16B slot s (0..3) of row r in a [256][32]bf16 tile.
// Verified R3/R6: SQ_LDS_BANK_CONFLICT == 0.
__device__ __forceinline__ int swz(int r, int s) {
  return ((r >> 1) << 7) + (((((r & 1) << 2) | s) ^ ((r >> 1) & 7)) << 4);
}

// ---------------- convert G (fp32 -> bf16), grid-stride ----------------
__global__ void convert_g_kernel(const float* __restrict__ in,
                                 unsigned short* __restrict__ out) {
  size_t nvec = (size_t)M_DIM * K_DIM / 8;
  size_t stride = (size_t)gridDim.x * blockDim.x;
  for (size_t i = (size_t)blockIdx.x * blockDim.x + threadIdx.x; i < nvec;
       i += stride) {
    const float4* p = (const float4*)(in + i * 8);
    float4 u0 = p[0], u1 = p[1];
    short8 s;
    s[0] = (short)f2bf(u0.x); s[1] = (short)f2bf(u0.y);
    s[2] = (short)f2bf(u0.z); s[3] = (short)f2bf(u0.w);
    s[4] = (short)f2bf(u1.x); s[5] = (short)f2bf(u1.y);
    s[6] = (short)f2bf(u1.z); s[7] = (short)f2bf(u1.w);
    *(short8*)(out + i * 8) = s;
  }
}

// ------- convert + transpose W via LDS: Wt[n][k] = bf16(W[k][n]) -------
__global__ void convert_w_kernel(const float* __restrict__ w,
                                 unsigned short* __restrict__ wt) {
  __shared__ float tile[64][65];
  int n0 = blockIdx.x * 64;
  int k0 = blockIdx.y * 64;
  int j = threadIdx.x & 63;
  int i0 = threadIdx.x >> 6;  // 0..3
#pragma unroll
  for (int ii = 0; ii < 16; ++ii) {
    int i = i0 * 16 + ii;
    tile[i][j] = w[(size_t)(k0 + i) * H_DIM + n0 + j];
  }
  __syncthreads();
#pragma unroll
  for (int ii = 0; ii < 16; ++ii) {
    int i = i0 * 16 + ii;
    wt[(size_t)(n0 + i) * H_DIM + k0 + j] = f2bf(tile[j][i]);
  }
}

// ---- GEMM: logits[row] += sum_col c[col] * tanh( A[row,:] . Bt[col,:] ) ----
// R11: ONE barrier per K-tile, no forced lgkmcnt(0), no sched_barrier pins.
// Compiler interleaves the 12 frag ds_reads with the 32 MFMAs via its own
// counted lgkmcnt; counted vmcnt(8) keeps 2 tiles of staging in flight.
// Live operand frags = 12 (48 VGPR) -- R6's proven no-spill budget.
// Hazard ledger:
//  - reads of tile t-1 are consumed by iter t-1's MFMAs (data dep => retired
//    before its barrier); stage->buf (t-1)&3 issues after that barrier. OK.
//  - vmcnt(8) at end of iter t certifies tile t+1's 4 stage-loads (oldest of
//    12 outstanding) before any wave reads them next iter (barrier follows).
__global__ __launch_bounds__(512, 2) void gemm_tanh_logits(
    const unsigned short* __restrict__ A,
    const unsigned short* __restrict__ Bt,
    const float* __restrict__ cvec,
    float* __restrict__ logits) {
  __shared__ unsigned short lds[4 * 16384];  // 4 bufs x (A 16KB + B 16KB)

  const int tid = threadIdx.x;
  const int wid = tid >> 6;
  const int lane = tid & 63;

  // R6 XCD map (verified): 4 ncols of one mrow land on one XCD -> A L2-reuse.
  int p = blockIdx.x;
  int logical = (p & 7) * 128 + (p >> 3);
  int mrow = logical >> 2;  // 0..255
  int ncol = logical & 3;   // 0..3

  const unsigned short* Ap = A + (size_t)mrow * BM * K_DIM;
  const unsigned short* Bp = Bt + (size_t)ncol * BN * K_DIM;

  const unsigned short *gA[2], *gB[2];
#pragma unroll
  for (int j = 0; j < 2; ++j) {
    int o = j * 8192 + tid * 16;
    int pr = o >> 7;
    int v = ((o >> 4) & 7) ^ (pr & 7);
    int r = (pr << 1) | (v >> 2);
    int s = v & 3;
    gA[j] = Ap + (size_t)r * K_DIM + s * 8;
    gB[j] = Bp + (size_t)r * K_DIM + s * 8;
  }
  const int ldst0 = wid * 512;
  const int ldst1 = wid * 512 + 4096;

  auto stageA = [&](int tt, int bi) {
    __builtin_amdgcn_global_load_lds(
        (const __attribute__((address_space(1))) unsigned int*)(gA[0] + tt * BKT),
        (__attribute__((address_space(3))) unsigned int*)(lds + bi * 16384 + ldst0),
        16, 0, 0);
    __builtin_amdgcn_global_load_lds(
        (const __attribute__((address_space(1))) unsigned int*)(gA[1] + tt * BKT),
        (__attribute__((address_space(3))) unsigned int*)(lds + bi * 16384 + ldst1),
        16, 0, 0);
  };
  auto stageB = [&](int tt, int bi) {
    __builtin_amdgcn_global_load_lds(
        (const __attribute__((address_space(1))) unsigned int*)(gB[0] + tt * BKT),
        (__attribute__((address_space(3))) unsigned int*)(lds + bi * 16384 + 8192 + ldst0),
        16, 0, 0);
    __builtin_amdgcn_global_load_lds(
        (const __attribute__((address_space(1))) unsigned int*)(gB[1] + tt * BKT),
        (__attribute__((address_space(3))) unsigned int*)(lds + bi * 16384 + 8192 + ldst1),
        16, 0, 0);
  };

  const int wm = wid >> 2;
  const int wn = wid & 3;
  const int fr = lane & 15;
  const int sl = lane >> 4;

  const int aoff = swz(wm * 128 + fr, sl) >> 1;
  const int boff = (swz(wn * 64 + fr, sl) >> 1) + 8192;

  f32x4 acc[8][4];
#pragma unroll
  for (int m = 0; m < 8; ++m)
#pragma unroll
    for (int n = 0; n < 4; ++n) acc[m][n] = (f32x4){0.f, 0.f, 0.f, 0.f};

  // prologue: stage tiles 0..2 (12 loads); vmcnt(8) -> tile 0 landed; barrier
  stageA(0, 0); stageB(0, 0);
  stageA(1, 1); stageB(1, 1);
  stageA(2, 2); stageB(2, 2);
  asm volatile("s_waitcnt vmcnt(8)" ::: "memory");
  __builtin_amdgcn_s_barrier();

#pragma unroll 4
  for (int t = 0; t < NTILES; ++t) {
    asm volatile("" ::: "memory");  // fence: nothing moves above the barrier
    if (t + DEPTH < NTILES) {
      stageA(t + DEPTH, (t + DEPTH) & 3);
      stageB(t + DEPTH, (t + DEPTH) & 3);
    }
    const unsigned short* L0 = lds + (t & 3) * 16384;
    short8 a[8], b[4];
#pragma unroll
    for (int n = 0; n < 4; ++n) b[n] = *(const short8*)(L0 + boff + n * 512);
#pragma unroll
    for (int m = 0; m < 8; ++m) a[m] = *(const short8*)(L0 + aoff + m * 512);
    // compiler interleaves counted lgkmcnt between reads and these MFMAs
#pragma unroll
    for (int m = 0; m < 8; ++m)
#pragma unroll
      for (int n = 0; n < 4; ++n)
        acc[m][n] = __builtin_amdgcn_mfma_f32_16x16x32_bf16(a[m], b[n],
                                                            acc[m][n], 0, 0, 0);
    // counted vmcnt: certify tile t+1 (oldest 4 of 12 outstanding stages)
    if (t < NTILES - DEPTH)
      asm volatile("s_waitcnt vmcnt(8)" ::: "memory");
    else if (t == NTILES - DEPTH)
      asm volatile("s_waitcnt vmcnt(4)" ::: "memory");
    else if (t == NTILES - 2)
      asm volatile("s_waitcnt vmcnt(0)" ::: "memory");
    __builtin_amdgcn_s_barrier();
  }

  // epilogue: logits[row] += sum_cols c[col]*tanh(acc)
  // C/D layout: col = lane&15, row = (lane>>4)*4 + j
  const int cgrp = lane >> 4;
  const int cidx = lane & 15;
  const int colb = ncol * BN + wn * 64;
  const int rowb = mrow * BM + wm * 128;
  float cw[4];
#pragma unroll
  for (int n = 0; n < 4; ++n) cw[n] = cvec[colb + n * 16 + cidx];
#pragma unroll
  for (int m = 0; m < 8; ++m) {
    float s0 = 0.f, s1 = 0.f, s2 = 0.f, s3 = 0.f;
#pragma unroll
    for (int n = 0; n < 4; ++n) {
      s0 += fast_tanh(acc[m][n][0]) * cw[n];
      s1 += fast_tanh(acc[m][n][1]) * cw[n];
      s2 += fast_tanh(acc[m][n][2]) * cw[n];
      s3 += fast_tanh(acc[m][n][3]) * cw[n];
    }
#pragma unroll
    for (int mask = 1; mask < 16; mask <<= 1) {
      s0 += __shfl_xor(s0, mask);
      s1 += __shfl_xor(s1, mask);
      s2 += __shfl_xor(s2, mask);
      s3 += __shfl_xor(s3, mask);
    }
    if (cidx == 0) {
      int row = rowb + m * 16 + cgrp * 4;
      atomicAdd(&logits[row + 0], s0);
      atomicAdd(&logits[row + 1], s1);
      atomicAdd(&logits[row + 2], s2);
      atomicAdd(&logits[row + 3], s3);
    }
  }
}

// -------- softmax over T (2048) per batch row, in-place on logits ----------
__global__ void softmax_kernel(float* __restrict__ la) {
  int b = blockIdx.x;
  float* row = la + (size_t)b * T_DIM;
  int tid = threadIdx.x;
  int wid = tid >> 6, lane = tid & 63;
  __shared__ float red[4];

  float v[8];
  float mx = -3.4e38f;
#pragma unroll
  for (int i = 0; i < 8; ++i) {
    v[i] = row[tid + i * 256];
    mx = fmaxf(mx, v[i]);
  }
#pragma unroll
  for (int mask = 32; mask >= 1; mask >>= 1) mx = fmaxf(mx, __shfl_xor(mx, mask));
  if (lane == 0) red[wid] = mx;
  __syncthreads();
  mx = fmaxf(fmaxf(red[0], red[1]), fmaxf(red[2], red[3]));
  __syncthreads();

  float sum = 0.f;
#pragma unroll
  for (int i = 0; i < 8; ++i) {
    v[i] = __expf(v[i] - mx);
    sum += v[i];
  }
#pragma unroll
  for (int mask = 32; mask >= 1; mask >>= 1) sum += __shfl_xor(sum, mask);
  if (lane == 0) red[wid] = sum;
  __syncthreads();
  sum = red[0] + red[1] + red[2] + red[3];
  float inv = 1.f / sum;
#pragma unroll
  for (int i = 0; i < 8; ++i) row[tid + i * 256] = v[i] * inv;
}

// --- context[b][h] = sum_t attn[b][t]*G[b][t][h], bf16 G, 16B/lane loads ---
__global__ void context_kernel(const unsigned short* __restrict__ Gb,
                               const float* __restrict__ attn,
                               float* __restrict__ ctx) {
  int tc = blockIdx.x;             // 0..7 (256 t each)
  int b = blockIdx.y;              // 0..31
  int th = threadIdx.x >> 7;       // 0..1 -> t-half of 128
  int h = (threadIdx.x & 127) * 8; // 0..1016
  const unsigned short* g =
      Gb + ((size_t)b * T_DIM + tc * 256 + th * 128) * H_DIM + h;
  const float* a = attn + b * T_DIM + tc * 256 + th * 128;
  float s[8];
#pragma unroll
  for (int j = 0; j < 8; ++j) s[j] = 0.f;
#pragma unroll 4
  for (int t = 0; t < 128; ++t) {
    short8 v = *(const short8*)(g + (size_t)t * H_DIM);
    float w = a[t];
#pragma unroll
    for (int j = 0; j < 8; ++j) s[j] += w * bf2f((unsigned short)v[j]);
  }
  float* cb = ctx + b * H_DIM + h;
#pragma unroll
  for (int j = 0; j < 8; ++j) atomicAdd(cb + j, s[j]);
}

extern "C" void kernel_launch(void* const* d_in, const int* in_sizes, int n_in,
                              void* d_out, int out_size, void* d_ws, size_t ws_size,
                              hipStream_t stream) {
  const float* G = (const float*)d_in[0];  // [32][2048][1024]
  const float* W = (const float*)d_in[1];  // [1024][1024]
  const float* c = (const float*)d_in[2];  // [1024]
  float* out = (float*)d_out;
  float* ctx = out;                         // [32][1024]
  float* attn = out + B_DIM * H_DIM;        // [32][2048] logits -> attn

  unsigned short* Gb = (unsigned short*)d_ws;                        // 128MB
  unsigned short* Wt = (unsigned short*)((char*)d_ws +
                                         (size_t)M_DIM * K_DIM * 2);  // 2MB

  hipMemsetAsync(d_out, 0, (size_t)out_size * sizeof(float), stream);

  convert_g_kernel<<<4096, 256, 0, stream>>>(G, Gb);
  convert_w_kernel<<<dim3(16, 16), 256, 0, stream>>>(W, Wt);
  gemm_tanh_logits<<<1024, 512, 0, stream>>>(Gb, Wt, c, attn);
  softmax_kernel<<<B_DIM, 256, 0, stream>>>(attn);
  context_kernel<<<dim3(8, 32), 256, 0, stream>>>(Gb, attn, ctx);
}